// Round 4
// baseline (39.422 us; speedup 1.0000x reference)
//
#include <hip/hip_runtime.h>
#include <math.h>

// Fused DETR HungarianMatcher cost matrix:
//   C[nq, t] = 5*L1(pred_cxcywh, tgt_cxcywh) + 2*focal_cls(prob[nq, lab[t]])
//              - 2*GIoU(pred_xyxy, tgt_xyxy)
// NQ = 14400, T = 1600. Output f32 [NQ, T].
//
// Round-4 structure: WAVE-PER-QUERY (latency/occupancy attack).
//  - block = 256 thr = 4 waves; wave w owns row q0+w. Lanes walk t in float4
//    quads: 400/64 = 6.25 iters -> cross-iteration pipelining.
//  - q-state is 9 scalar regs (not arrays); live set ~55 VGPR -> 6-8 waves/SIMD
//    (round-3 had ~16 outputs in flight, ~170 VGPR, 2-3 waves/SIMD, 1.56 iters:
//    every load->gather->compute chain exposed).
//  - class gather: ds_read_b32 from the wave's own 80-float row (320 B) instead
//    of ds_read_b128 over 80 rows -> far fewer bank conflicts on the dep path.

#define NCLS  80
#define QTILE 4
#define NTHR  256

__global__ __launch_bounds__(NTHR)
void matcher_cost_kernel(const float* __restrict__ logits,   // [NQ, 80]
                         const float* __restrict__ pboxes,   // [NQ, 4] cxcywh
                         const float* __restrict__ tboxes,   // [T, 4] xyxy
                         const int*   __restrict__ tlabels,  // [T]
                         float* __restrict__ out,            // [NQ, T]
                         int NQ, int T)
{
    __shared__ float ccT[QTILE][NCLS];   // [q][label] : 2*cls + 2 (weights folded)

    const int tid = threadIdx.x;
    const int q0  = blockIdx.x * QTILE;   // NQ % QTILE == 0 (14400/4)

    // --- focal class-cost table (320 entries, coalesced logits reads) ---
    for (int i = tid; i < QTILE * NCLS; i += NTHR) {
        int q = i / NCLS, lab = i - q * NCLS;
        float x = logits[(size_t)(q0 + q) * NCLS + lab];
        float p = 1.0f / (1.0f + __expf(-x));
        float pos = 0.25f * (1.0f - p) * (1.0f - p) * (-__logf(p + 1e-8f));
        float neg = 0.75f * p * p * (-__logf(1.0f - p + 1e-8f));
        ccT[q][lab] = 2.0f * (pos - neg) + 2.0f;
    }

    const int wave = tid >> 6;
    const int lane = tid & 63;
    const int gq   = q0 + wave;

    // --- this wave's query: 9 scalar registers ---
    float4 pb = reinterpret_cast<const float4*>(pboxes)[gq];   // wave-uniform
    const float qcx = pb.x, qcy = pb.y, qw = pb.z, qh = pb.w;
    const float qx1 = pb.x - 0.5f * pb.z, qy1 = pb.y - 0.5f * pb.w;
    const float qx2 = pb.x + 0.5f * pb.z, qy2 = pb.y + 0.5f * pb.w;
    const float qa  = (qx2 - qx1) * (qy2 - qy1);               // like ref

    __syncthreads();

    const float4* tb4  = reinterpret_cast<const float4*>(tboxes);
    const int4*   lb4  = reinterpret_cast<const int4*>(tlabels);
    const float*  crow = ccT[wave];
    const int nquad = T >> 2;                                  // 400
    float4* orow = reinterpret_cast<float4*>(out + (size_t)gq * T);

    for (int quad = lane; quad < nquad; quad += 64) {
        const int t0 = quad << 2;
        float4 b0 = tb4[t0], b1 = tb4[t0 + 1], b2 = tb4[t0 + 2], b3 = tb4[t0 + 3];
        int4 L = lb4[quad];
        // scalar gathers from this wave's 320 B row
        float c0 = crow[L.x], c1 = crow[L.y], c2 = crow[L.z], c3 = crow[L.w];

        float4 v;
        float* vv = &v.x;
        const float cls[4] = {c0, c1, c2, c3};
        const float4 bb[4] = {b0, b1, b2, b3};
#pragma unroll
        for (int j = 0; j < 4; ++j) {
            const float bx1 = bb[j].x, by1 = bb[j].y, bx2 = bb[j].z, by2 = bb[j].w;
            const float bw = bx2 - bx1, bh = by2 - by1;
            const float bcx = 0.5f * (bx1 + bx2), bcy = 0.5f * (by1 + by2);
            const float ba = bw * bh;

            float l1 = (fabsf(qcx - bcx) + fabsf(qcy - bcy))
                     + (fabsf(qw  - bw ) + fabsf(qh  - bh ));

            float ix1 = fmaxf(qx1, bx1), iy1 = fmaxf(qy1, by1);
            float ix2 = fminf(qx2, bx2), iy2 = fminf(qy2, by2);
            float iwd = ix2 - ix1,       ihd = iy2 - iy1;
            float inter = fmaxf(iwd, 0.0f) * fmaxf(ihd, 0.0f);
            float uni = (qa + ba) - inter;
            // enclosing box via max+min=a+b: cw,ch > 0 always
            float cw = (qw + bw) - iwd;
            float ch = (qh + bh) - ihd;
            float ca = cw * ch;

            // cost = 5*l1 + (2*cls+2) - 2*(inter*ca + uni^2)/(uni*ca)
            float base  = fmaf(5.0f, l1, cls[j]);
            float r     = __builtin_amdgcn_rcpf(uni * ca);   // ~1 ulp
            float numer = fmaf(uni, uni, inter * ca);
            vv[j] = fmaf(-2.0f * numer, r, base);
        }
        orow[quad] = v;   // 64 lanes -> 1 KB contiguous
    }
}

extern "C" void kernel_launch(void* const* d_in, const int* in_sizes, int n_in,
                              void* d_out, int out_size, void* d_ws, size_t ws_size,
                              hipStream_t stream) {
    const float* logits  = (const float*)d_in[0];  // [16,900,80]
    const float* pboxes  = (const float*)d_in[1];  // [16,900,4]
    const float* tboxes  = (const float*)d_in[2];  // [1600,4]
    const int*   tlabels = (const int*)d_in[3];    // [1600]
    float* out = (float*)d_out;

    const int NQ = in_sizes[1] / 4;   // 14400
    const int T  = in_sizes[2] / 4;   // 1600

    const int nblocks = (NQ + QTILE - 1) / QTILE;  // 3600
    matcher_cost_kernel<<<nblocks, NTHR, 0, stream>>>(logits, pboxes, tboxes,
                                                      tlabels, out, NQ, T);
}

// Round 5
// 31.664 us; speedup vs baseline: 1.2450x; 1.2450x over previous
//
#include <hip/hip_runtime.h>
#include <math.h>

// Fused DETR HungarianMatcher cost matrix:
//   C[nq, t] = 5*L1(pred_cxcywh, tgt_cxcywh) + 2*focal_cls(prob[nq, lab[t]])
//              - 2*GIoU(pred_xyxy, tgt_xyxy)
// NQ = 14400, T = 1600. Output f32 [NQ, T].
//
// Round-5: ISSUE-SLOT attack (R1-R4 showed dur tracks per-output instruction
// count, not occupancy).
//  - v2f (ext_vector_type(2)) packed math over target-pairs: add/sub/mul/fma
//    emit v_pk_*_f32 (2 outputs per instruction). min/max/rcp stay scalar.
//  - lanes walk t in PAIRS: 800/256 = 3.125 iters (R3's 1.56 had 22% tail
//    imbalance), float2 stores (512B/wave, still full cache lines).
//  - per-target derived values amortized across the 4 queries of the block;
//    one ds_read_b128 class gather per 2 targets serves all 4 queries.
//  - single rcp per output, weights folded into table, 32-bit store indexing.

#define NCLS  80
#define QTILE 4
#define NTHR  256

typedef float v2f __attribute__((ext_vector_type(2)));

static __device__ __forceinline__ v2f v2(float a, float b) { v2f r; r.x = a; r.y = b; return r; }
static __device__ __forceinline__ v2f vmax2(v2f a, v2f b) { return v2(fmaxf(a.x, b.x), fmaxf(a.y, b.y)); }
static __device__ __forceinline__ v2f vmin2(v2f a, v2f b) { return v2(fminf(a.x, b.x), fminf(a.y, b.y)); }

__global__ __launch_bounds__(NTHR)
void matcher_cost_kernel(const float* __restrict__ logits,   // [NQ, 80]
                         const float* __restrict__ pboxes,   // [NQ, 4] cxcywh
                         const float* __restrict__ tboxes,   // [T, 4] xyxy
                         const int*   __restrict__ tlabels,  // [T]
                         float* __restrict__ out,            // [NQ, T]
                         int NQ, int T)
{
    __shared__ float ccT[NCLS][QTILE];   // [label][q] : 2*cls + 2 (weights folded)

    const int tid = threadIdx.x;
    const int q0  = blockIdx.x * QTILE;   // NQ % 4 == 0

    // --- focal table: coalesced read of the block's contiguous 320 logits ---
    for (int i = tid; i < QTILE * NCLS; i += NTHR) {
        int q = i / NCLS, lab = i - q * NCLS;
        float x = logits[(size_t)q0 * NCLS + i];
        float p = 1.0f / (1.0f + __expf(-x));
        float pos = 0.25f * (1.0f - p) * (1.0f - p) * (-__logf(p + 1e-8f));
        float neg = 0.75f * p * p * (-__logf(1.0f - p + 1e-8f));
        ccT[lab][q] = 2.0f * (pos - neg) + 2.0f;
    }

    // --- per-query state: wave-uniform (compiler should scalarize to SGPR) ---
    float qx1[QTILE], qy1[QTILE], qx2[QTILE], qy2[QTILE];
    float qcx[QTILE], qcy[QTILE], qw[QTILE], qh[QTILE], qa[QTILE];
#pragma unroll
    for (int q = 0; q < QTILE; ++q) {
        float4 pb = reinterpret_cast<const float4*>(pboxes)[q0 + q];
        qcx[q] = pb.x; qcy[q] = pb.y; qw[q] = pb.z; qh[q] = pb.w;
        qx1[q] = pb.x - 0.5f * pb.z;  qy1[q] = pb.y - 0.5f * pb.w;
        qx2[q] = pb.x + 0.5f * pb.z;  qy2[q] = pb.y + 0.5f * pb.w;
        qa[q]  = (qx2[q] - qx1[q]) * (qy2[q] - qy1[q]);
    }
    __syncthreads();

    const float4* tb4 = reinterpret_cast<const float4*>(tboxes);
    const int2*   lb2 = reinterpret_cast<const int2*>(tlabels);
    const float4* ccv = reinterpret_cast<const float4*>(ccT);

    const int npair = T >> 1;                        // 800
    float2* obase = reinterpret_cast<float2*>(out) + (size_t)q0 * npair;

    for (int pair = tid; pair < npair; pair += NTHR) {
        const int t0 = pair << 1;
        float4 b0 = tb4[t0], b1 = tb4[t0 + 1];
        int2 L = lb2[pair];
        float4 c0 = ccv[L.x], c1 = ccv[L.y];   // 4 q-values per target

        // packed target state: lane j of v2f = target t0+j
        v2f bx1 = v2(b0.x, b1.x), by1 = v2(b0.y, b1.y);
        v2f bx2 = v2(b0.z, b1.z), by2 = v2(b0.w, b1.w);
        v2f bw  = bx2 - bx1;                 // pk
        v2f bh  = by2 - by1;                 // pk
        v2f bcx = 0.5f * (bx1 + bx2);        // pk add + pk mul
        v2f bcy = 0.5f * (by1 + by2);
        v2f ba  = bw * bh;                   // pk

#pragma unroll
        for (int q = 0; q < QTILE; ++q) {
            // L1: packed subs, scalar adds with free |.| input modifiers
            v2f dcx = qcx[q] - bcx, dcy = qcy[q] - bcy;
            v2f dw  = qw[q]  - bw,  dh  = qh[q]  - bh;
            float l1a = (fabsf(dcx.x) + fabsf(dcy.x)) + (fabsf(dw.x) + fabsf(dh.x));
            float l1b = (fabsf(dcx.y) + fabsf(dcy.y)) + (fabsf(dw.y) + fabsf(dh.y));

            // intersection (min/max scalar, rest packed)
            v2f ix1 = vmax2(v2(qx1[q], qx1[q]), bx1);
            v2f iy1 = vmax2(v2(qy1[q], qy1[q]), by1);
            v2f ix2 = vmin2(v2(qx2[q], qx2[q]), bx2);
            v2f iy2 = vmin2(v2(qy2[q], qy2[q]), by2);
            v2f iwd = ix2 - ix1, ihd = iy2 - iy1;
            v2f iw = vmax2(iwd, v2(0.f, 0.f));
            v2f ih = vmax2(ihd, v2(0.f, 0.f));
            v2f inter = iw * ih;
            v2f uni = (qa[q] + ba) - inter;
            // enclosing box via max+min = a+b identity (cw,ch > 0 always)
            v2f cw = (qw[q] + bw) - iwd;
            v2f ch = (qh[q] + bh) - ihd;
            v2f ca = cw * ch;

            float clsa = (q == 0) ? c0.x : (q == 1) ? c0.y : (q == 2) ? c0.z : c0.w;
            float clsb = (q == 0) ? c1.x : (q == 1) ? c1.y : (q == 2) ? c1.z : c1.w;

            // cost = 5*l1 + (2*cls+2) - 2*(inter*ca + uni^2)/(uni*ca)
            v2f base = v2(fmaf(5.0f, l1a, clsa), fmaf(5.0f, l1b, clsb));
            v2f den  = uni * ca;                                  // pk
            v2f r    = v2(__builtin_amdgcn_rcpf(den.x),
                          __builtin_amdgcn_rcpf(den.y));          // trans x2
            v2f ica  = inter * ca;                                // pk
            v2f num  = uni * uni + ica;                           // pk fma
            v2f nr   = num * r;                                   // pk
            v2f res  = -2.0f * nr + base;                         // pk fma

            obase[q * npair + pair] = make_float2(res.x, res.y);  // 32-bit index
        }
    }
}

extern "C" void kernel_launch(void* const* d_in, const int* in_sizes, int n_in,
                              void* d_out, int out_size, void* d_ws, size_t ws_size,
                              hipStream_t stream) {
    const float* logits  = (const float*)d_in[0];  // [16,900,80]
    const float* pboxes  = (const float*)d_in[1];  // [16,900,4]
    const float* tboxes  = (const float*)d_in[2];  // [1600,4]
    const int*   tlabels = (const int*)d_in[3];    // [1600]
    float* out = (float*)d_out;

    const int NQ = in_sizes[1] / 4;   // 14400
    const int T  = in_sizes[2] / 4;   // 1600

    const int nblocks = (NQ + QTILE - 1) / QTILE;  // 3600
    matcher_cost_kernel<<<nblocks, NTHR, 0, stream>>>(logits, pboxes, tboxes,
                                                      tlabels, out, NQ, T);
}

// Round 7
// 31.184 us; speedup vs baseline: 1.2642x; 1.0154x over previous
//
#include <hip/hip_runtime.h>
#include <math.h>

// Fused DETR HungarianMatcher cost matrix:
//   C[nq, t] = 5*L1(pred_cxcywh, tgt_cxcywh) + 2*focal_cls(prob[nq, lab[t]])
//              - 2*GIoU(pred_xyxy, tgt_xyxy)
// NQ = 14400, T = 1600. Output f32 [NQ, T].
//
// Round-7 = Round-6 with the overlap identity FIXED:
//   1-D signed overlap of intervals (c1,w1),(c2,w2):
//     iwd = (w1+w2)/2 - max(|c1-c2|, |w1-w2|/2)     [R6 dropped the 2nd term:
//   wrong when one interval contains the other -> absmax 2.4e6]
//   enclosing extent: cw = (w1+w2) - iwd  (signed iwd; > 0 always)
//   |c1-c2| is shared with the L1 term.
// Kept from R6: v2f packed math (v_pk_*_f32), branch-free clamped-index
// register prefetch, one rcp per output, folded weights, 32-bit store index.

#define NCLS  80
#define QTILE 4
#define NTHR  256

typedef float v2f __attribute__((ext_vector_type(2)));

static __device__ __forceinline__ v2f v2(float a, float b) { v2f r; r.x = a; r.y = b; return r; }

__global__ __launch_bounds__(NTHR)
void matcher_cost_kernel(const float* __restrict__ logits,   // [NQ, 80]
                         const float* __restrict__ pboxes,   // [NQ, 4] cxcywh
                         const float* __restrict__ tboxes,   // [T, 4] xyxy
                         const int*   __restrict__ tlabels,  // [T]
                         float* __restrict__ out,            // [NQ, T]
                         int NQ, int T)
{
    __shared__ float ccT[NCLS][QTILE];   // [label][q] : 2*cls + 2 (weights folded)

    const int tid = threadIdx.x;
    const int q0  = blockIdx.x * QTILE;   // NQ % 4 == 0

    // --- focal table: coalesced read of the block's contiguous 320 logits ---
    for (int i = tid; i < QTILE * NCLS; i += NTHR) {
        int q = i / NCLS, lab = i - q * NCLS;
        float x = logits[(size_t)q0 * NCLS + i];
        float p = 1.0f / (1.0f + __expf(-x));
        float pos = 0.25f * (1.0f - p) * (1.0f - p) * (-__logf(p + 1e-8f));
        float neg = 0.75f * p * p * (-__logf(1.0f - p + 1e-8f));
        ccT[lab][q] = 2.0f * (pos - neg) + 2.0f;
    }

    // --- per-query state (wave-uniform): 7 scalars per q ---
    float qcx[QTILE], qcy[QTILE], qw[QTILE], qh[QTILE];
    float qwh[QTILE], qhh[QTILE], qa[QTILE];
#pragma unroll
    for (int q = 0; q < QTILE; ++q) {
        float4 pb = reinterpret_cast<const float4*>(pboxes)[q0 + q];
        qcx[q] = pb.x; qcy[q] = pb.y; qw[q] = pb.z; qh[q] = pb.w;
        qwh[q] = 0.5f * pb.z; qhh[q] = 0.5f * pb.w;
        qa[q]  = pb.z * pb.w;   // == (x2-x1)*(y2-y1) for w,h>0
    }
    __syncthreads();

    const float4* tb4 = reinterpret_cast<const float4*>(tboxes);
    const int2*   lb2 = reinterpret_cast<const int2*>(tlabels);
    const float4* ccv = reinterpret_cast<const float4*>(ccT);

    const int npair = T >> 1;                        // 800
    float2* obase = reinterpret_cast<float2*>(out) + (size_t)q0 * npair;

    int pair = tid;                                  // tid < 256 <= npair: valid
    float4 b0 = tb4[pair * 2], b1 = tb4[pair * 2 + 1];
    int2 L = lb2[pair];

    for (;;) {
        const int  nxt  = pair + NTHR;
        const bool more = nxt < npair;
        const int  nc   = more ? nxt : pair;         // clamped: branch-free loads
        float4 nb0 = tb4[nc * 2], nb1 = tb4[nc * 2 + 1];
        int2   nL  = lb2[nc];

        // class gather: one b128 per target serves all 4 queries
        float4 c0 = ccv[L.x], c1 = ccv[L.y];

        // shared per-target math (element j of v2f = target 2*pair+j)
        v2f bX1 = v2(b0.x, b1.x), bY1 = v2(b0.y, b1.y);
        v2f bX2 = v2(b0.z, b1.z), bY2 = v2(b0.w, b1.w);
        v2f bw  = bX2 - bX1,      bh  = bY2 - bY1;
        v2f bcx = 0.5f * (bX1 + bX2);
        v2f bcy = 0.5f * (bY1 + bY2);
        v2f ba  = bw * bh;
        v2f bwh = 0.5f * bw,      bhh = 0.5f * bh;

#pragma unroll
        for (int q = 0; q < QTILE; ++q) {
            v2f dcx = qcx[q] - bcx, dcy = qcy[q] - bcy;
            v2f dw  = qw[q]  - bw,  dh  = qh[q]  - bh;
            v2f adx = v2(fabsf(dcx.x), fabsf(dcx.y));
            v2f ady = v2(fabsf(dcy.x), fabsf(dcy.y));
            v2f l1  = (adx + ady) + v2(fabsf(dw.x) + fabsf(dh.x),
                                       fabsf(dw.y) + fabsf(dh.y));

            // half-extent sums & diffs
            v2f hw  = qwh[q] + bwh,  hh  = qhh[q] + bhh;
            v2f dwh = qwh[q] - bwh,  dhh = qhh[q] - bhh;
            // signed overlap: iwd = hw - max(|dcx|, |dwh|)   (containment-safe)
            v2f ewx = v2(fmaxf(adx.x, fabsf(dwh.x)), fmaxf(adx.y, fabsf(dwh.y)));
            v2f ewy = v2(fmaxf(ady.x, fabsf(dhh.x)), fmaxf(ady.y, fabsf(dhh.y)));
            v2f iwd = hw - ewx,      ihd = hh - ewy;
            v2f iw  = v2(fmaxf(iwd.x, 0.f), fmaxf(iwd.y, 0.f));
            v2f ih  = v2(fmaxf(ihd.x, 0.f), fmaxf(ihd.y, 0.f));
            v2f inter = iw * ih;
            v2f uni = (qa[q] + ba) - inter;
            // enclosing extent: cw = (qw+bw) - iwd = 2*hw - iwd  (> 0 always)
            v2f cw = 2.0f * hw - iwd;
            v2f ch = 2.0f * hh - ihd;
            v2f ca = cw * ch;

            float clsa = (q == 0) ? c0.x : (q == 1) ? c0.y : (q == 2) ? c0.z : c0.w;
            float clsb = (q == 0) ? c1.x : (q == 1) ? c1.y : (q == 2) ? c1.z : c1.w;

            // cost = 5*l1 + (2*cls+2) - 2*(inter*ca + uni^2)/(uni*ca)
            v2f base = 5.0f * l1 + v2(clsa, clsb);
            v2f den  = uni * ca;
            v2f r    = v2(__builtin_amdgcn_rcpf(den.x),
                          __builtin_amdgcn_rcpf(den.y));     // ~1 ulp
            v2f num  = uni * uni + inter * ca;
            v2f res  = -2.0f * (num * r) + base;

            obase[q * npair + pair] = make_float2(res.x, res.y);
        }

        if (!more) break;
        pair = nxt; b0 = nb0; b1 = nb1; L = nL;
    }
}

extern "C" void kernel_launch(void* const* d_in, const int* in_sizes, int n_in,
                              void* d_out, int out_size, void* d_ws, size_t ws_size,
                              hipStream_t stream) {
    const float* logits  = (const float*)d_in[0];  // [16,900,80]
    const float* pboxes  = (const float*)d_in[1];  // [16,900,4]
    const float* tboxes  = (const float*)d_in[2];  // [1600,4]
    const int*   tlabels = (const int*)d_in[3];    // [1600]
    float* out = (float*)d_out;

    const int NQ = in_sizes[1] / 4;   // 14400
    const int T  = in_sizes[2] / 4;   // 1600

    const int nblocks = (NQ + QTILE - 1) / QTILE;  // 3600
    matcher_cost_kernel<<<nblocks, NTHR, 0, stream>>>(logits, pboxes, tboxes,
                                                      tlabels, out, NQ, T);
}